// Round 6
// baseline (164.691 us; speedup 1.0000x reference)
//
#include <hip/hip_runtime.h>

// GRU with per-row sequence lengths. B=4096, T=200, I=64, H=128 (hardcoded).
// Output[b] = h after seq_lengths[b] steps from h0=0.
//
// Round-6 structure (r5 base + three fixes):
//  - 256 blocks x 512 threads (8 waves, 2/SIMD), 16 rows/block. Wave owns 16
//    h-cols (48 gate cols): 12 h-MFMA + 6 x-MFMA (pipelined 1 step ahead),
//    B-frags (18 x h8 = 72 VGPR) resident.
//  - Slab LDS layout, row stride 40 halves (80B = 20 words): A-frag reads are
//    conflict-free (quad idx = (5*lrow+kgrp) mod 8 is a perfect spread) and
//    16B-aligned. r5's HP=136 (68w = 4 mod 32) was ~4-8-way conflicted.
//  - Staggered x staging: stage step at (t&7)==blockIdx%7 de-phases the HBM
//    bursts across blocks (r5: all 256 blocks staged at t=0 mod 8 -> ~4MB
//    synchronized burst -> vmcnt drain stall at every stage barrier).
//  - Unroll-by-2 with ping-pong x-part accumulator sets: no acc copies,
//    compile-time LDS buffer indices.

#define I_DIM 64
#define H_DIM 128
#define CH 8     // x-chunk steps
#define RS 40    // slab row stride in halves (80 B)

typedef _Float16 h8 __attribute__((ext_vector_type(8)));
typedef _Float16 h4 __attribute__((ext_vector_type(4)));
typedef float f4 __attribute__((ext_vector_type(4)));

__device__ __forceinline__ float fast_rcp(float x) { return __builtin_amdgcn_rcpf(x); }
__device__ __forceinline__ float sigmoid_f(float x) { return fast_rcp(1.0f + __expf(-x)); }
__device__ __forceinline__ float tanh_f(float x) { return 1.0f - 2.0f * fast_rcp(__expf(2.0f * x) + 1.0f); }

__global__ __launch_bounds__(512, 2)
void gru_seq_kernel(const float* __restrict__ input,
                    const int* __restrict__ seq_lengths,
                    const float* __restrict__ W_ih,
                    const float* __restrict__ W_hh,
                    const float* __restrict__ b_ih,
                    const float* __restrict__ b_hh,
                    float* __restrict__ out,
                    int B, int T) {
    // h: [buf][slab(k/32)][row][RS]; x ring: [slot][step][slab][row][RS]
    __shared__ __align__(16) _Float16 h_lds[2][4][16][RS];
    __shared__ __align__(16) _Float16 x_lds[2][CH][2][16][RS];

    const int tid  = threadIdx.x;
    const int lane = tid & 63;
    const int w    = tid >> 6;     // wave 0..7
    const int base = blockIdx.x * 16;
    const int boff = blockIdx.x % 7;   // stage-phase stagger (0..6; write >=1 barrier before first read)

    const int lrow  = lane & 15;   // MFMA A-row / C-col index
    const int kgrp  = lane >> 4;   // 0..3
    const int kgrp8 = kgrp * 8;
    const int kgrp4 = kgrp * 4;

    // ---- sequence lengths ----
    int Lq[4];
#pragma unroll
    for (int q = 0; q < 4; ++q) {
        int gr = base + kgrp4 + q;
        Lq[q] = (gr < B) ? seq_lengths[gr] : 0;
    }
    int Lmax = 0;
    for (int i = 0; i < 16; ++i) {
        int gr = base + i;
        int L = (gr < B) ? seq_lengths[gr] : 0;
        Lmax = max(Lmax, L);
    }
    if (Lmax > T) Lmax = T;

    // ---- biases (C col = w*16 + lrow) ----
    const int c0 = w * 16 + lrow;
    const float br  = b_ih[c0] + b_hh[c0];
    const float bz  = b_ih[H_DIM + c0] + b_hh[H_DIM + c0];
    const float bnh = b_hh[2 * H_DIM + c0];
    const float bnx = b_ih[2 * H_DIM + c0];

    // ---- resident B-fragments: Wcat[j][k], k 0..127 = W_hh, 128..191 = W_ih ----
    h8 bw[18];
#pragma unroll
    for (int gate = 0; gate < 3; ++gate) {
        const int j = gate * H_DIM + c0;
#pragma unroll
        for (int kt = 0; kt < 6; ++kt) {
            const int kb = kt * 32 + kgrp8;
            const float* src = (kt < 4) ? (W_hh + j * H_DIM + kb)
                                        : (W_ih + j * I_DIM + (kb - H_DIM));
            f4 f0 = *(const f4*)(src);
            f4 f1 = *(const f4*)(src + 4);
            h8 v;
            v[0] = (_Float16)f0[0]; v[1] = (_Float16)f0[1];
            v[2] = (_Float16)f0[2]; v[3] = (_Float16)f0[3];
            v[4] = (_Float16)f1[0]; v[5] = (_Float16)f1[1];
            v[6] = (_Float16)f1[2]; v[7] = (_Float16)f1[3];
            bw[gate * 6 + kt] = v;
        }
    }

    // ---- zero h buf0 data region (h(0)=0): 4 slabs x 16 rows x 32 halves ----
    {
        int idx = tid * 4;                       // 2048 halves / 512 threads
        int sl = idx >> 9, r = (idx >> 5) & 15, cc = idx & 31;
        *(h4*)&h_lds[0][sl][r][cc] = h4{0, 0, 0, 0};
    }

    // ---- x staging geometry: 32 thr/row; thread covers steps si0+2j, 4 floats ----
    const int srow  = tid >> 5;                  // 0..15
    const int si0   = (tid & 31) >> 4;           // 0..1
    const int icol  = (tid & 15) * 4;            // 0,4,..,60
    const int xslab = icol >> 5;
    const int xcol  = icol & 31;
    const int gxr   = base + srow;
    const float* xsrc = input + (size_t)gxr * T * I_DIM;
    const bool xok = (gxr < B);

    // prologue: stage chunk 0 into slot 0
    if (Lmax > 0) {
#pragma unroll
        for (int j = 0; j < 4; ++j) {
            int s = si0 + 2 * j;
            f4 xv = f4{0.f, 0.f, 0.f, 0.f};
            if (xok && s < T) xv = *(const f4*)(xsrc + (size_t)s * I_DIM + icol);
            h4 hv;
            hv[0] = (_Float16)xv[0]; hv[1] = (_Float16)xv[1];
            hv[2] = (_Float16)xv[2]; hv[3] = (_Float16)xv[3];
            *(h4*)&x_lds[0][s][xslab][srow][xcol] = hv;
        }
    }
    __syncthreads();

    // ---- x-part accumulators, ping-pong sets indexed by step parity ----
    f4 xar[2], xaz[2], xan[2];
    xar[0] = f4{br, br, br, br};
    xaz[0] = f4{bz, bz, bz, bz};
    xan[0] = f4{bnx, bnx, bnx, bnx};
    if (Lmax > 0) {
        h8 xg0 = *(const h8*)&x_lds[0][0][0][lrow][kgrp8];
        h8 xg1 = *(const h8*)&x_lds[0][0][1][lrow][kgrp8];
        xar[0] = __builtin_amdgcn_mfma_f32_16x16x32_f16(xg0, bw[4],  xar[0], 0, 0, 0);
        xar[0] = __builtin_amdgcn_mfma_f32_16x16x32_f16(xg1, bw[5],  xar[0], 0, 0, 0);
        xaz[0] = __builtin_amdgcn_mfma_f32_16x16x32_f16(xg0, bw[10], xaz[0], 0, 0, 0);
        xaz[0] = __builtin_amdgcn_mfma_f32_16x16x32_f16(xg1, bw[11], xaz[0], 0, 0, 0);
        xan[0] = __builtin_amdgcn_mfma_f32_16x16x32_f16(xg0, bw[16], xan[0], 0, 0, 0);
        xan[0] = __builtin_amdgcn_mfma_f32_16x16x32_f16(xg1, bw[17], xan[0], 0, 0, 0);
    }

    const int hs = c0 >> 5;     // h-write slab
    const int hc = c0 & 31;     // h-write col in slab

    float hreg[4]  = {0.f, 0.f, 0.f, 0.f};
    float hnreg[4] = {0.f, 0.f, 0.f, 0.f};

    // ---- one step; P = step parity (compile-time): read h buf P, write buf P^1 ----
#define STEP(P, TC) do {                                                              \
        const int t_ = (TC);                                                          \
        f4 xv0, xv1, xv2, xv3;                                                        \
        const bool do_stage = ((t_ & 7) == boff) && (((t_ >> 3) + 1) * CH < Lmax);    \
        if (do_stage) {                                                               \
            const int t0 = ((t_ >> 3) + 1) * CH;                                      \
            xv0 = xv1 = xv2 = xv3 = f4{0.f, 0.f, 0.f, 0.f};                           \
            if (xok) {                                                                \
                int s0 = t0 + si0;                                                    \
                if (s0     < T) xv0 = *(const f4*)(xsrc + (size_t)(s0    ) * I_DIM + icol); \
                if (s0 + 2 < T) xv1 = *(const f4*)(xsrc + (size_t)(s0 + 2) * I_DIM + icol); \
                if (s0 + 4 < T) xv2 = *(const f4*)(xsrc + (size_t)(s0 + 4) * I_DIM + icol); \
                if (s0 + 6 < T) xv3 = *(const f4*)(xsrc + (size_t)(s0 + 6) * I_DIM + icol); \
            }                                                                         \
        }                                                                             \
        h8 af0 = *(const h8*)&h_lds[P][0][lrow][kgrp8];                               \
        h8 af1 = *(const h8*)&h_lds[P][1][lrow][kgrp8];                               \
        h8 af2 = *(const h8*)&h_lds[P][2][lrow][kgrp8];                               \
        h8 af3 = *(const h8*)&h_lds[P][3][lrow][kgrp8];                               \
        f4 ar  = xar[P];                                                              \
        f4 az  = xaz[P];                                                              \
        f4 axn = xan[P];                                                              \
        f4 anh = f4{bnh, bnh, bnh, bnh};                                              \
        __builtin_amdgcn_s_setprio(1);                                                \
        ar  = __builtin_amdgcn_mfma_f32_16x16x32_f16(af0, bw[0],  ar,  0, 0, 0);      \
        az  = __builtin_amdgcn_mfma_f32_16x16x32_f16(af0, bw[6],  az,  0, 0, 0);      \
        anh = __builtin_amdgcn_mfma_f32_16x16x32_f16(af0, bw[12], anh, 0, 0, 0);      \
        ar  = __builtin_amdgcn_mfma_f32_16x16x32_f16(af1, bw[1],  ar,  0, 0, 0);      \
        az  = __builtin_amdgcn_mfma_f32_16x16x32_f16(af1, bw[7],  az,  0, 0, 0);      \
        anh = __builtin_amdgcn_mfma_f32_16x16x32_f16(af1, bw[13], anh, 0, 0, 0);      \
        ar  = __builtin_amdgcn_mfma_f32_16x16x32_f16(af2, bw[2],  ar,  0, 0, 0);      \
        az  = __builtin_amdgcn_mfma_f32_16x16x32_f16(af2, bw[8],  az,  0, 0, 0);      \
        anh = __builtin_amdgcn_mfma_f32_16x16x32_f16(af2, bw[14], anh, 0, 0, 0);      \
        ar  = __builtin_amdgcn_mfma_f32_16x16x32_f16(af3, bw[3],  ar,  0, 0, 0);      \
        az  = __builtin_amdgcn_mfma_f32_16x16x32_f16(af3, bw[9],  az,  0, 0, 0);      \
        anh = __builtin_amdgcn_mfma_f32_16x16x32_f16(af3, bw[15], anh, 0, 0, 0);      \
        if (t_ + 1 < Lmax) {   /* x-part for step t+1 (independent work) */           \
            const int sl_ = ((t_ + 1) >> 3) & 1, ss_ = (t_ + 1) & 7;                  \
            h8 xg0 = *(const h8*)&x_lds[sl_][ss_][0][lrow][kgrp8];                    \
            h8 xg1 = *(const h8*)&x_lds[sl_][ss_][1][lrow][kgrp8];                    \
            f4 a0 = f4{br, br, br, br};                                               \
            f4 a1 = f4{bz, bz, bz, bz};                                               \
            f4 a2 = f4{bnx, bnx, bnx, bnx};                                           \
            a0 = __builtin_amdgcn_mfma_f32_16x16x32_f16(xg0, bw[4],  a0, 0, 0, 0);    \
            a1 = __builtin_amdgcn_mfma_f32_16x16x32_f16(xg0, bw[10], a1, 0, 0, 0);    \
            a2 = __builtin_amdgcn_mfma_f32_16x16x32_f16(xg0, bw[16], a2, 0, 0, 0);    \
            a0 = __builtin_amdgcn_mfma_f32_16x16x32_f16(xg1, bw[5],  a0, 0, 0, 0);    \
            a1 = __builtin_amdgcn_mfma_f32_16x16x32_f16(xg1, bw[11], a1, 0, 0, 0);    \
            a2 = __builtin_amdgcn_mfma_f32_16x16x32_f16(xg1, bw[17], a2, 0, 0, 0);    \
            xar[(P) ^ 1] = a0; xaz[(P) ^ 1] = a1; xan[(P) ^ 1] = a2;                  \
        }                                                                             \
        __builtin_amdgcn_s_setprio(0);                                                \
        _Pragma("unroll")                                                             \
        for (int q = 0; q < 4; ++q) {                                                 \
            float r    = sigmoid_f(ar[q]);                                            \
            float z    = sigmoid_f(az[q]);                                            \
            float n    = tanh_f(axn[q] + r * anh[q]);                                 \
            float hnew = n + z * (hreg[q] - n);                                       \
            hreg[q] = hnew;                                                           \
            if (t_ < Lq[q]) hnreg[q] = hnew;                                          \
            h_lds[(P) ^ 1][hs][kgrp4 + q][hc] = (_Float16)hnew;                       \
        }                                                                             \
        if (do_stage) {                                                               \
            const int ws_ = ((t_ >> 3) + 1) & 1;                                      \
            h4 hv;                                                                    \
            hv[0] = (_Float16)xv0[0]; hv[1] = (_Float16)xv0[1];                       \
            hv[2] = (_Float16)xv0[2]; hv[3] = (_Float16)xv0[3];                       \
            *(h4*)&x_lds[ws_][si0][xslab][srow][xcol] = hv;                           \
            hv[0] = (_Float16)xv1[0]; hv[1] = (_Float16)xv1[1];                       \
            hv[2] = (_Float16)xv1[2]; hv[3] = (_Float16)xv1[3];                       \
            *(h4*)&x_lds[ws_][si0 + 2][xslab][srow][xcol] = hv;                       \
            hv[0] = (_Float16)xv2[0]; hv[1] = (_Float16)xv2[1];                       \
            hv[2] = (_Float16)xv2[2]; hv[3] = (_Float16)xv2[3];                       \
            *(h4*)&x_lds[ws_][si0 + 4][xslab][srow][xcol] = hv;                       \
            hv[0] = (_Float16)xv3[0]; hv[1] = (_Float16)xv3[1];                       \
            hv[2] = (_Float16)xv3[2]; hv[3] = (_Float16)xv3[3];                       \
            *(h4*)&x_lds[ws_][si0 + 6][xslab][srow][xcol] = hv;                       \
        }                                                                             \
        __syncthreads();                                                              \
    } while (0)

    int t = 0;
    for (; t + 1 < Lmax; t += 2) {
        STEP(0, t);
        STEP(1, t + 1);
    }
    if (t < Lmax) STEP(0, t);

#undef STEP

    // ---- store hn ----
#pragma unroll
    for (int q = 0; q < 4; ++q) {
        int gr = base + kgrp4 + q;
        if (gr < B) out[(size_t)gr * H_DIM + c0] = hnreg[q];
    }
}

extern "C" void kernel_launch(void* const* d_in, const int* in_sizes, int n_in,
                              void* d_out, int out_size, void* d_ws, size_t ws_size,
                              hipStream_t stream) {
    const float* input = (const float*)d_in[0];
    const int*   seq   = (const int*)d_in[1];
    const float* W_ih  = (const float*)d_in[2];
    const float* W_hh  = (const float*)d_in[3];
    const float* b_ih  = (const float*)d_in[4];
    const float* b_hh  = (const float*)d_in[5];
    float* out = (float*)d_out;

    const int B = in_sizes[1];
    const int T = in_sizes[0] / (B * I_DIM);

    const int grid = (B + 15) / 16;
    gru_seq_kernel<<<grid, 512, 0, stream>>>(input, seq, W_ih, W_hh, b_ih, b_hh, out, B, T);
}